// Round 8
// baseline (446.719 us; speedup 1.0000x reference)
//
#include <hip/hip_runtime.h>
#include <hip/hip_bf16.h>
#include <math.h>

// Problem constants
#define B_   32
#define S_   128
#define V_   30000
#define D_   300
#define P_   200
#define NT   8192         // 2*B*S token rows: x1 rows 0..4095, x2 rows 4096..8191
#define NT1  4096

typedef __hip_bfloat16 bf16;
typedef __attribute__((ext_vector_type(8))) __bf16 bf16x8;
typedef __attribute__((ext_vector_type(4))) float f32x4;

__device__ __forceinline__ float b2f(bf16 v) { return __bfloat162float(v); }
__device__ __forceinline__ short f2s(float v) { bf16 h = __float2bfloat16(v); return *(short*)&h; }
__device__ __forceinline__ float s2f(short s) { bf16 h; *(short*)&h = s; return __bfloat162float(h); }

// ---------------------------------------------------------------------------
// Fused weight conversion (8 standard matrices): fp32 [K][N] (optionally two
// sources concat along N) -> bf16 WT[Npad][Kpad], zero-padded.
// ---------------------------------------------------------------------------
struct ConvTable {
    const float* W1[8]; const float* W2[8]; bf16* dst[8];
    int K[8], N1[8], N2[8], Kpad[8];
    unsigned long long base[8]; unsigned long long total;
};

__global__ void k_convw(ConvTable T) {
    unsigned long long idx = (unsigned long long)blockIdx.x * 256 + threadIdx.x;
    if (idx >= T.total) return;
    int e = 0;
#pragma unroll
    for (int i = 1; i < 8; ++i) if (idx >= T.base[i]) e = i;
    unsigned long long local = idx - T.base[e];
    int Kpad = T.Kpad[e];
    int n = (int)(local / Kpad);
    int k = (int)(local - (unsigned long long)n * Kpad);
    float v = 0.f;
    if (k < T.K[e]) {
        if (n < T.N1[e]) v = T.W1[e][(size_t)k * T.N1[e] + n];
        else if (n < T.N1[e] + T.N2[e]) v = T.W2[e][(size_t)k * T.N2[e] + (n - T.N1[e])];
    }
    T.dst[e][local] = __float2bfloat16(v);
}

// ---------------------------------------------------------------------------
// Combined cmp_W1 conversion. Cat@W1 with Cat=[E,A,E-A,E*A] decomposes as
// E@(W1a+W1c) + A@(W1b-W1c) + EA@W1d (W1 split in 300-row blocks a,b,c,d).
// dst [256][960]: seg0 k0..300 = W1a+W1c; seg1 320+.. = W1b-W1c; seg2 640+..
// = W1d. Zero pads. W is cmp_W1 [1200][200].
// ---------------------------------------------------------------------------
__global__ void k_convc(const float* __restrict__ W, bf16* __restrict__ dst) {
    int idx = blockIdx.x * 256 + threadIdx.x;
    if (idx >= 256 * 960) return;
    int n = idx / 960, k = idx - n * 960;
    int sel = k / 320, kc = k - sel * 320;
    float v = 0.f;
    if (kc < 300 && n < 200) {
        if (sel == 0)      v = W[(size_t)kc * 200 + n] + W[(size_t)(600 + kc) * 200 + n];
        else if (sel == 1) v = W[(size_t)(300 + kc) * 200 + n] - W[(size_t)(600 + kc) * 200 + n];
        else               v = W[(size_t)(900 + kc) * 200 + n];
    }
    dst[idx] = __float2bfloat16(v);
}

// ---------------------------------------------------------------------------
// fp32 transposes for the skinny tail (one dispatch)
// ---------------------------------------------------------------------------
__global__ void k_convt(const float* __restrict__ W1, const float* __restrict__ W2,
                        const float* __restrict__ W3, float* __restrict__ T1,
                        float* __restrict__ T2, float* __restrict__ T3) {
    int idx = blockIdx.x * 256 + threadIdx.x;
    if (idx < 160000) {                         // 200 x 800
        int n = idx / 800, k = idx - n * 800;
        T1[idx] = W1[k * 200 + n];
    } else if (idx < 200000) {                  // 200 x 200
        int l = idx - 160000;
        int n = l / 200, k = l - n * 200;
        T2[l] = W2[k * 200 + n];
    } else if (idx < 200600) {                  // 3 x 200
        int l = idx - 200000;
        int n = l / 200, k = l - n * 200;
        T3[l] = W3[k * 3 + n];
    }
}

// ---------------------------------------------------------------------------
// Skinny GEMM for tiny M: one wave per output element (validated round 6).
// ---------------------------------------------------------------------------
__global__ __launch_bounds__(256) void k_skinny(
    const float* __restrict__ A, const float* __restrict__ WT,
    const float* __restrict__ bias, float* __restrict__ C,
    int M, int N, int K, int act) {
    int wave = (blockIdx.x * 256 + threadIdx.x) >> 6;
    int lane = threadIdx.x & 63;
    if (wave >= M * N) return;
    int m = wave / N, n = wave - m * N;
    const float4* a4 = (const float4*)(A + (size_t)m * K);
    const float4* w4 = (const float4*)(WT + (size_t)n * K);
    int K4 = K >> 2;
    float acc = 0.f;
    for (int i = lane; i < K4; i += 64) {
        float4 av = a4[i], wv = w4[i];
        acc += av.x * wv.x + av.y * wv.y + av.z * wv.z + av.w * wv.w;
    }
#pragma unroll
    for (int off = 32; off > 0; off >>= 1) acc += __shfl_down(acc, off, 64);
    if (lane == 0) {
        float v = acc + bias[n];
        if (act == 1) v = fmaxf(v, 0.f);
        C[(size_t)m * N + n] = v;
    }
}

// ---------------------------------------------------------------------------
// Embedding gather: fp32 emb -> bf16 E
// ---------------------------------------------------------------------------
__global__ void k_embed(const int* __restrict__ x1, const int* __restrict__ x2,
                        const float* __restrict__ emb, bf16* __restrict__ E) {
    int idx = blockIdx.x * 256 + threadIdx.x;
    if (idx >= NT * D_) return;
    int r = idx / D_;
    int d = idx - r * D_;
    int tok = (r < NT1) ? x1[r] : x2[r - NT1];
    if ((unsigned)tok >= (unsigned)V_) tok = 0;
    E[idx] = __float2bfloat16(emb[(size_t)tok * D_ + d]);
}

// ---------------------------------------------------------------------------
// MFMA GEMM with register double-buffer prefetch.
// Block tile 64(M) x 128(N): 4 waves 2x2, each 32x64 via 16x16x32 MFMA.
// WT pre-transposed/padded. CAT=1: virtual K-concat over {A,A2,A3}, each
// [M,300] with 320-padded segments (Kpad=960); sel = k0/320 is wave-uniform.
// ---------------------------------------------------------------------------
#define TM 64
#define TN 128
#define TK 32
#define TKP 40

template <int CAT>
__global__ __launch_bounds__(256) void k_mfma_gemm(
    const bf16* __restrict__ A, const bf16* __restrict__ A2,
    const bf16* __restrict__ A3, int lda,
    const bf16* __restrict__ WT, int Kpad, int K,
    bf16* __restrict__ C, int ldc, int Ntot, int N1,
    const float* __restrict__ bias1, const float* __restrict__ bias2,
    int act1, int act2)
{
    __shared__ short As[TM][TKP];
    __shared__ short Bs[TN][TKP];
    int tid = threadIdx.x;
    int w = tid >> 6, lane = tid & 63, quad = lane >> 4, l16 = lane & 15;
    int bm = blockIdx.y * TM;
    int bn = blockIdx.x * TN;
    int wr = (w & 1) * 32;
    int wc = (w >> 1) * 64;

    int ar = tid >> 2;            // 0..63 : A row in tile
    int ac = (tid & 3) * 8;       // 0/8/16/24
    int br = tid >> 1;            // 0..127 : B n-row
    int bc = (tid & 1) * 16;      // 0/16
    const short* Wsh = (const short*)WT;

    f32x4 acc[2][4];
#pragma unroll
    for (int i = 0; i < 2; ++i)
#pragma unroll
        for (int j = 0; j < 4; ++j)
#pragma unroll
            for (int r = 0; r < 4; ++r) acc[i][j][r] = 0.f;

    short4 pa0, pa1, pb0, pb1, pb2, pb3;

    auto loadA = [&](int k0) {
        if (CAT == 0) {
            int k = k0 + ac;
            const short* src = (const short*)A + (size_t)(bm + ar) * lda + k;
            if (k + 8 <= K) {
                pa0 = ((const short4*)src)[0];
                pa1 = ((const short4*)src)[1];
            } else {
                short tmp[8];
#pragma unroll
                for (int i = 0; i < 8; ++i) tmp[i] = (k + i < K) ? src[i] : (short)0;
                pa0 = *(short4*)&tmp[0]; pa1 = *(short4*)&tmp[4];
            }
        } else {
            int sel = k0 / 320;                         // wave-uniform
            const short* base = (sel == 0) ? (const short*)A
                              : (sel == 1) ? (const short*)A2 : (const short*)A3;
            int k = (k0 - sel * 320) + ac;
            const short* src = base + (size_t)(bm + ar) * 300 + k;
            if (k + 8 <= 300) {
                pa0 = ((const short4*)src)[0];
                pa1 = ((const short4*)src)[1];
            } else {
                short tmp[8];
#pragma unroll
                for (int i = 0; i < 8; ++i) tmp[i] = (k + i < 300) ? src[i] : (short)0;
                pa0 = *(short4*)&tmp[0]; pa1 = *(short4*)&tmp[4];
            }
        }
    };
    auto loadB = [&](int k0) {
        const short* src = Wsh + (size_t)(bn + br) * Kpad + k0 + bc;
        pb0 = ((const short4*)src)[0];
        pb1 = ((const short4*)src)[1];
        pb2 = ((const short4*)src)[2];
        pb3 = ((const short4*)src)[3];
    };

    loadA(0); loadB(0);
    for (int k0 = 0; k0 < Kpad; k0 += TK) {
        // commit prefetched tile to LDS
        *(short4*)&As[ar][ac] = pa0;
        *(short4*)&As[ar][ac + 4] = pa1;
        {
            short4* q = (short4*)&Bs[br][bc];
            q[0] = pb0; q[1] = pb1; q[2] = pb2; q[3] = pb3;
        }
        __syncthreads();
        // prefetch next tile into registers (overlaps with MFMA below)
        if (k0 + TK < Kpad) { loadA(k0 + TK); loadB(k0 + TK); }
        {
            bf16x8 a[2], b[4];
#pragma unroll
            for (int mt = 0; mt < 2; ++mt)
                a[mt] = *(const bf16x8*)&As[wr + mt * 16 + l16][quad * 8];
#pragma unroll
            for (int nt = 0; nt < 4; ++nt)
                b[nt] = *(const bf16x8*)&Bs[wc + nt * 16 + l16][quad * 8];
#pragma unroll
            for (int mt = 0; mt < 2; ++mt)
#pragma unroll
                for (int nt = 0; nt < 4; ++nt)
                    acc[mt][nt] = __builtin_amdgcn_mfma_f32_16x16x32_bf16(a[mt], b[nt], acc[mt][nt], 0, 0, 0);
        }
        __syncthreads();
    }
#pragma unroll
    for (int mt = 0; mt < 2; ++mt) {
        int row = bm + wr + mt * 16 + quad * 4;
#pragma unroll
        for (int nt = 0; nt < 4; ++nt) {
            int col = bn + wc + nt * 16 + l16;
            if (col >= Ntot) continue;
            float bv; int act;
            if (col < N1) { bv = bias1[col]; act = act1; }
            else          { bv = bias2[col - N1]; act = act2; }
#pragma unroll
            for (int r = 0; r < 4; ++r) {
                float v = acc[mt][nt][r] + bv;
                if (act == 1) v = fmaxf(v, 0.f);
                else if (act == 2) v = 1.f / (1.f + expf(-v));
                C[(size_t)(row + r) * ldc + col] = __float2bfloat16(v);
            }
        }
    }
}

// ---------------------------------------------------------------------------
// Highway combine from packed h|t buffer: X = t*h + (1-t)*X
// ---------------------------------------------------------------------------
__global__ void k_highway2(const bf16* __restrict__ HT, int ldht, int nseg,
                           bf16* __restrict__ X, int width) {
    int idx = blockIdx.x * 256 + threadIdx.x;
    if (idx >= NT * width) return;
    int m = idx / width, d = idx - m * width;
    float h = b2f(HT[(size_t)m * ldht + d]);
    float t = b2f(HT[(size_t)m * ldht + nseg + d]);
    float x = b2f(X[idx]);
    X[idx] = __float2bfloat16(t * h + (1.f - t) * x);
}

// ---------------------------------------------------------------------------
// Transpose x2-halves of two [NT,P] matrices into [B,P,S]; y selects (P,Q).
// ---------------------------------------------------------------------------
__global__ void k_transpose2(const bf16* __restrict__ srcP, bf16* __restrict__ dstP,
                             const bf16* __restrict__ srcQ, bf16* __restrict__ dstQ) {
    int idx = blockIdx.x * 256 + threadIdx.x;
    if (idx >= B_ * P_ * S_) return;
    const bf16* src = blockIdx.y ? srcQ : srcP;
    bf16* dst = blockIdx.y ? dstQ : dstP;
    int j = idx & (S_ - 1);
    int rest = idx >> 7;
    int p = rest % P_;
    int b = rest / P_;
    dst[idx] = src[((size_t)(b * S_ + j)) * P_ + p];
}

// ---------------------------------------------------------------------------
// sim kernel (validated round 7): i-tiled, LDS broadcast, fast rcp.
// ---------------------------------------------------------------------------
__global__ __launch_bounds__(256) void k_sim2(const bf16* __restrict__ Pmat,
                                              const bf16* __restrict__ Qmat,
                                              const bf16* __restrict__ PT,
                                              const bf16* __restrict__ QT,
                                              float* __restrict__ SIM) {
    __shared__ float qp[8][P_][2];
    int blk = blockIdx.x;
    int b = blk >> 4;
    int it = blk & 15;
    int tid = threadIdx.x;
    int j = tid & 127, h = tid >> 7;
    int row0 = b * 128 + it * 8;
    for (int x = tid; x < 8 * P_; x += 256) {
        int r = x / P_, c = x - r * P_;
        qp[r][c][0] = b2f(Qmat[(size_t)(row0 + r) * P_ + c]);
        qp[r][c][1] = b2f(Pmat[(size_t)(row0 + r) * P_ + c]);
    }
    __syncthreads();
    const bf16* ptb = PT + (size_t)b * P_ * S_;
    const bf16* qtb = QT + (size_t)b * P_ * S_;
    float acc[4] = {0.f, 0.f, 0.f, 0.f};
    for (int p = 0; p < P_; ++p) {
        float v = b2f(ptb[p * S_ + j]);
        float u = b2f(qtb[p * S_ + j]);
#pragma unroll
        for (int r = 0; r < 4; ++r) {
            int i = h * 4 + r;
            float2 w = *(const float2*)&qp[i][p][0];
            float d = w.x - u;
            acc[r] += w.y * v + __builtin_amdgcn_rcpf(1.f + fabsf(d));
        }
    }
#pragma unroll
    for (int r = 0; r < 4; ++r) {
        int i = it * 8 + h * 4 + r;
        SIM[((size_t)(b * 128 + i)) * S_ + j] = acc[r];
    }
}

// ---------------------------------------------------------------------------
// Merged softmax-weighted average + fused EA=E*ATT product.
// grid 8192 = 4096 beta + 4096 alpha; OUT/EA row = blk's token row.
// ---------------------------------------------------------------------------
__global__ __launch_bounds__(256) void k_av2(const float* __restrict__ SIM,
                                             const bf16* __restrict__ E,
                                             bf16* __restrict__ OUT,
                                             bf16* __restrict__ EA) {
    int blk = blockIdx.x;
    int kind = blk >> 12;            // 0 = beta (rows), 1 = alpha (cols)
    int blk2 = blk & 4095;
    int b = blk2 >> 7, r = blk2 & 127;
    int t = threadIdx.x;
    __shared__ float w[S_];
    __shared__ float red[S_];
    float x = 0.f;
    if (t < 128) {
        x = (kind == 0) ? SIM[(size_t)blk2 * S_ + t]
                        : SIM[((size_t)b * S_ + t) * S_ + r];
        red[t] = x;
    }
    __syncthreads();
    for (int s = 64; s > 0; s >>= 1) {
        if (t < s) red[t] = fmaxf(red[t], red[t + s]);
        __syncthreads();
    }
    float mx = red[0];
    __syncthreads();
    float ex = 0.f;
    if (t < 128) { ex = expf(x - mx); red[t] = ex; }
    __syncthreads();
    for (int s = 64; s > 0; s >>= 1) {
        if (t < s) red[t] += red[t + s];
        __syncthreads();
    }
    if (t < 128) w[t] = ex / red[0];
    __syncthreads();
    if (t < 150) {
        int orow_idx = (kind == 0) ? blk2 : (NT1 + blk2);
        const bf16* Esrc = E + (kind == 0 ? (size_t)NT1 * D_ : 0) + (size_t)b * S_ * D_;
        const unsigned short* ebase = (const unsigned short*)Esrc + 2 * t;
        float a0 = 0.f, a1 = 0.f;
        for (int s = 0; s < S_; ++s) {
            unsigned int uv = *(const unsigned int*)(ebase + (size_t)s * D_);
            float lo = __uint_as_float(uv << 16);
            float hi = __uint_as_float(uv & 0xffff0000u);
            float ws = w[s];
            a0 += ws * lo;
            a1 += ws * hi;
        }
        unsigned int o = (unsigned int)(unsigned short)f2s(a0)
                       | ((unsigned int)(unsigned short)f2s(a1) << 16);
        *(unsigned int*)((unsigned short*)OUT + (size_t)orow_idx * D_ + 2 * t) = o;
        // fused EA = E[row] * ATT[row]
        unsigned int ev = *(const unsigned int*)((const unsigned short*)E + (size_t)orow_idx * D_ + 2 * t);
        float e0 = __uint_as_float(ev << 16);
        float e1 = __uint_as_float(ev & 0xffff0000u);
        unsigned int o2 = (unsigned int)(unsigned short)f2s(a0 * e0)
                        | ((unsigned int)(unsigned short)f2s(a1 * e1) << 16);
        *(unsigned int*)((unsigned short*)EA + (size_t)orow_idx * D_ + 2 * t) = o2;
    }
}

// ---------------------------------------------------------------------------
// Pool: out[b] = concat(max_i v1, max_j v2, sum_i v1, sum_j v2)  [B,4P] fp32
// ---------------------------------------------------------------------------
__global__ __launch_bounds__(256) void k_pool(const bf16* __restrict__ V,
                                              float* __restrict__ OUT) {
    int b = blockIdx.x;
    int c = threadIdx.x;
    if (c >= P_) return;
    const bf16* v1 = V + (size_t)b * S_ * P_;
    const bf16* v2 = V + (size_t)(NT1 + b * S_) * P_;
    float mx1 = -INFINITY, mx2 = -INFINITY, s1 = 0.f, s2 = 0.f;
    for (int i = 0; i < S_; ++i) {
        float a = b2f(v1[(size_t)i * P_ + c]);
        mx1 = fmaxf(mx1, a); s1 += a;
        float bb = b2f(v2[(size_t)i * P_ + c]);
        mx2 = fmaxf(mx2, bb); s2 += bb;
    }
    float* o = OUT + (size_t)b * 4 * P_;
    o[c] = mx1; o[P_ + c] = mx2; o[2 * P_ + c] = s1; o[3 * P_ + c] = s2;
}

// Sentinel fill (diagnostic: absmax ~555 => ws_size too small)
__global__ void k_fillf(float* dst, int n, float v) {
    int i = blockIdx.x * 256 + threadIdx.x;
    if (i < n) dst[i] = v;
}

// ---------------------------------------------------------------------------
// Launch
// ---------------------------------------------------------------------------
extern "C" void kernel_launch(void* const* d_in, const int* in_sizes, int n_in,
                              void* d_out, int out_size, void* d_ws, size_t ws_size,
                              hipStream_t stream) {
    const int* x1 = (const int*)d_in[0];
    const int* x2 = (const int*)d_in[1];
    const float* emb = (const float*)d_in[2];
    const float *hw1_Wh = (const float*)d_in[3],  *hw1_bh = (const float*)d_in[4];
    const float *hw1_Wt = (const float*)d_in[5],  *hw1_bt = (const float*)d_in[6];
    const float *hw2_Wh = (const float*)d_in[7],  *hw2_bh = (const float*)d_in[8];
    const float *hw2_Wt = (const float*)d_in[9],  *hw2_bt = (const float*)d_in[10];
    const float *mul_W1 = (const float*)d_in[11], *mul_b1 = (const float*)d_in[12];
    const float *mul_W2 = (const float*)d_in[13], *mul_b2 = (const float*)d_in[14];
    const float *dist_W1 = (const float*)d_in[15], *dist_b1 = (const float*)d_in[16];
    const float *dist_W2 = (const float*)d_in[17], *dist_b2 = (const float*)d_in[18];
    const float *cmp_W1 = (const float*)d_in[19], *cmp_b1 = (const float*)d_in[20];
    const float *cmp_W2 = (const float*)d_in[21], *cmp_b2 = (const float*)d_in[22];
    const float *chw1_Wh = (const float*)d_in[23], *chw1_bh = (const float*)d_in[24];
    const float *chw1_Wt = (const float*)d_in[25], *chw1_bt = (const float*)d_in[26];
    const float *chw2_Wh = (const float*)d_in[27], *chw2_bh = (const float*)d_in[28];
    const float *chw2_Wt = (const float*)d_in[29], *chw2_bt = (const float*)d_in[30];
    const float *agg_W1 = (const float*)d_in[31], *agg_b1 = (const float*)d_in[32];
    const float *agg_W2 = (const float*)d_in[33], *agg_b2 = (const float*)d_in[34];
    const float *out_W = (const float*)d_in[35], *out_b = (const float*)d_in[36];

    // ---- Workspace layout (elems) ----
    const size_t nED = (size_t)NT * D_;        // 2,457,600
    const size_t nEP = (size_t)NT * P_;        // 1,638,400
    const size_t nCht = (size_t)NT * 600;      // 4,915,200
    const size_t nTR = (size_t)B_ * P_ * S_;   //   819,200
    const size_t nWT = 1220608;                // converted bf16 weights total
    const size_t nWTf = 200600;                // fp32 transposed tail weights
    size_t bf16_elems = 3 * nED + 2 * nEP + nCht + nWT;   // E, ATT, EA + P,Q + Cht + weights
    size_t f32_elems = (size_t)B_ * 4 * P_ + 2 * (size_t)B_ * P_ + nWTf;
    size_t need = bf16_elems * 2 + f32_elems * 4 + 64;
    if (ws_size < need) {
        k_fillf<<<dim3(1), dim3(256), 0, stream>>>((float*)d_out, B_ * 3, 555.f);
        return;
    }
    bf16* Eb  = (bf16*)d_ws;            // [NT,300]
    bf16* A2b = Eb + nED;               // [NT,300] ATT
    bf16* EAb = A2b + nED;              // [NT,300] E*ATT
    bf16* Pb  = EAb + nED;              // [NT,200] mul proj -> V
    bf16* Qb  = Pb + nEP;               // [NT,200] dist proj
    bf16* Cht = Qb + nEP;               // [NT,600] packed h|t / hidden / PT/QT/SIM
    bf16* WTp = Cht + nCht;             // converted bf16 weights pool
    float* POOL = (float*)(WTp + nWT);  // [B,4P]
    float* G1 = POOL + (size_t)B_ * 4 * P_;
    float* G2 = G1 + (size_t)B_ * P_;
    float* WT_a1 = G2 + (size_t)B_ * P_;  // [200][800] fp32
    float* WT_a2 = WT_a1 + 160000;        // [200][200] fp32
    float* WT_o  = WT_a2 + 40000;         // [3][200] fp32
    // overlays inside Cht:
    bf16* PTb = Cht;
    bf16* QTb = Cht + nTR;
    float* SIM = (float*)(Cht + 2 * nTR);

    // converted-weight sub-buffers (elems), Npad mult of 128
    bf16* WT_hw1 = WTp + 0;        // 640x320
    bf16* WT_hw2 = WTp + 204800;   // 640x320
    bf16* WT_md  = WTp + 409600;   // 512x320 (mul_W1 | dist_W1)
    bf16* WT_m2  = WTp + 573440;   // 256x224
    bf16* WT_d2  = WTp + 630784;   // 256x224
    bf16* WT_c1  = WTp + 688128;   // 256x960 (combined cmp_W1)
    bf16* WT_c2  = WTp + 933888;   // 256x224
    bf16* WT_ch1 = WTp + 991232;   // 512x224 (chw1_Wh | chw1_Wt)
    bf16* WT_ch2 = WTp + 1105920;  // 512x224

    dim3 blk256(256);

    // 0. weight conversions
    ConvTable T;
    const float* s1[8] = {hw1_Wh, hw2_Wh, mul_W1, mul_W2, dist_W2, cmp_W2, chw1_Wh, chw2_Wh};
    const float* s2[8] = {hw1_Wt, hw2_Wt, dist_W1, nullptr, nullptr, nullptr, chw1_Wt, chw2_Wt};
    bf16* dsts[8] = {WT_hw1, WT_hw2, WT_md, WT_m2, WT_d2, WT_c2, WT_ch1, WT_ch2};
    int Ks[8]  = {300, 300, 300, 200, 200, 200, 200, 200};
    int N1s[8] = {300, 300, 200, 200, 200, 200, 200, 200};
    int N2s[8] = {300, 300, 200, 0, 0, 0, 200, 200};
    int Kps[8] = {320, 320, 320, 224, 224, 224, 224, 224};
    int Nps[8] = {640, 640, 512, 256, 256, 256, 512, 512};
    unsigned long long base = 0;
    for (int i = 0; i < 8; ++i) {
        T.W1[i] = s1[i]; T.W2[i] = s2[i]; T.dst[i] = dsts[i];
        T.K[i] = Ks[i]; T.N1[i] = N1s[i]; T.N2[i] = N2s[i]; T.Kpad[i] = Kps[i];
        T.base[i] = base;
        base += (unsigned long long)Kps[i] * Nps[i];
    }
    T.total = base;   // 974,848
    k_convw<<<dim3((unsigned)((base + 255) / 256)), blk256, 0, stream>>>(T);
    k_convc<<<dim3((256 * 960 + 255) / 256), blk256, 0, stream>>>(cmp_W1, WT_c1);
    k_convt<<<dim3((200600 + 255) / 256), blk256, 0, stream>>>(agg_W1, agg_W2, out_W,
                                                               WT_a1, WT_a2, WT_o);

    // 1. embed
    k_embed<<<dim3((NT * D_ + 255) / 256), blk256, 0, stream>>>(x1, x2, emb, Eb);

    int hwyD = (NT * D_ + 255) / 256, hwyP = (NT * P_ + 255) / 256;

    // 2-3. embedding highway stack: combined h|t GEMM (N=600) + combine
    k_mfma_gemm<0><<<dim3(5, 128), blk256, 0, stream>>>(Eb, nullptr, nullptr, 300, WT_hw1, 320, 300,
        Cht, 600, 600, 300, hw1_bh, hw1_bt, 1, 2);
    k_highway2<<<dim3(hwyD), blk256, 0, stream>>>(Cht, 600, 300, Eb, 300);
    k_mfma_gemm<0><<<dim3(5, 128), blk256, 0, stream>>>(Eb, nullptr, nullptr, 300, WT_hw2, 320, 300,
        Cht, 600, 600, 300, hw2_bh, hw2_bt, 1, 2);
    k_highway2<<<dim3(hwyD), blk256, 0, stream>>>(Cht, 600, 300, Eb, 300);

    // 4-5. mul+dist W1 combined (N=400) -> Cht; then W2s -> Pb, Qb
    k_mfma_gemm<0><<<dim3(4, 128), blk256, 0, stream>>>(Eb, nullptr, nullptr, 300, WT_md, 320, 300,
        Cht, 400, 400, 200, mul_b1, dist_b1, 1, 1);
    k_mfma_gemm<0><<<dim3(2, 128), blk256, 0, stream>>>(Cht, nullptr, nullptr, 400, WT_m2, 224, 200,
        Pb, 200, 200, 200, mul_b2, mul_b2, 1, 1);
    k_mfma_gemm<0><<<dim3(2, 128), blk256, 0, stream>>>(Cht + 200, nullptr, nullptr, 400, WT_d2, 224, 200,
        Qb, 200, 200, 200, dist_b2, dist_b2, 1, 1);

    // 6. transpose x2-halves into Cht overlay (one dispatch, y selects P/Q)
    int nTRb = (int)((nTR + 255) / 256);
    k_transpose2<<<dim3(nTRb, 2), blk256, 0, stream>>>(
        Pb + (size_t)NT1 * P_, PTb, Qb + (size_t)NT1 * P_, QTb);

    // 7. sim
    k_sim2<<<dim3(B_ * 16), blk256, 0, stream>>>(Pb, Qb, PTb, QTb, SIM);

    // 8. attention (merged beta+alpha) + fused EA product
    k_av2<<<dim3(2 * NT1), blk256, 0, stream>>>(SIM, Eb, A2b, EAb);

    // 9. compare ff: decomposed CAT GEMM (virtual K-concat {E, ATT, EA}, K=960)
    k_mfma_gemm<1><<<dim3(2, 128), blk256, 0, stream>>>(Eb, A2b, EAb, 300, WT_c1, 960, 300,
        Cht, 200, 200, 200, cmp_b1, cmp_b1, 1, 1);
    k_mfma_gemm<0><<<dim3(2, 128), blk256, 0, stream>>>(Cht, nullptr, nullptr, 200, WT_c2, 224, 200,
        Pb, 200, 200, 200, cmp_b2, cmp_b2, 1, 1);

    // 10-11. compare highway stack (combined N=400 GEMMs)
    k_mfma_gemm<0><<<dim3(4, 128), blk256, 0, stream>>>(Pb, nullptr, nullptr, 200, WT_ch1, 224, 200,
        Cht, 400, 400, 200, chw1_bh, chw1_bt, 1, 2);
    k_highway2<<<dim3(hwyP), blk256, 0, stream>>>(Cht, 400, 200, Pb, 200);
    k_mfma_gemm<0><<<dim3(4, 128), blk256, 0, stream>>>(Pb, nullptr, nullptr, 200, WT_ch2, 224, 200,
        Cht, 400, 400, 200, chw2_bh, chw2_bt, 1, 2);
    k_highway2<<<dim3(hwyP), blk256, 0, stream>>>(Cht, 400, 200, Pb, 200);

    // 12. pool
    k_pool<<<dim3(B_), blk256, 0, stream>>>(Pb, POOL);

    // 13-15. aggregate ff + final linear: wave-per-output skinny GEMMs
    k_skinny<<<dim3(1600), blk256, 0, stream>>>(POOL, WT_a1, agg_b1, G1, B_, P_, 800, 1);
    k_skinny<<<dim3(1600), blk256, 0, stream>>>(G1, WT_a2, agg_b2, G2, B_, P_, 200, 1);
    k_skinny<<<dim3(24), blk256, 0, stream>>>(G2, WT_o, out_b, (float*)d_out, B_, 3, 200, 0);
}